// Round 1
// baseline (465.102 us; speedup 1.0000x reference)
//
#include <hip/hip_runtime.h>
#include <cmath>

#define NLEVELS 16
#define HSIZE   (1 << 19)     // hashmap size, power of two
#define HMASK   (HSIZE - 1)

struct LevelParams {
    int res[NLEVELS];
    int r2mod[NLEVELS];       // (res*res) % HSIZE
};

__global__ __launch_bounds__(256)
void hashgrid_fwd(const float* __restrict__ x,
                  const float* __restrict__ emb,
                  float* __restrict__ out,
                  LevelParams lp, int npts)
{
    __shared__ float sx[256 * 3];

    const int tid        = threadIdx.x;
    const int block_base = blockIdx.x * 256;
    const int nfl        = npts * 3;
    const int base3      = block_base * 3;

    // Coalesced cooperative load of this block's 256 points (768 floats) into LDS.
    #pragma unroll
    for (int k = 0; k < 3; ++k) {
        int idx = base3 + tid + k * 256;
        if (idx < nfl) sx[tid + k * 256] = x[idx];
    }
    __syncthreads();

    const int p = block_base + tid;
    if (p >= npts) return;

    const float x0 = sx[tid * 3 + 0];
    const float x1 = sx[tid * 3 + 1];
    const float x2 = sx[tid * 3 + 2];

    const float2* __restrict__ e2 = (const float2*)emb;

    float2 v[NLEVELS];

    #pragma unroll
    for (int l = 0; l < NLEVELS; ++l) {
        const int   res = lp.res[l];       // constant index -> SGPR
        const int   r2  = lp.r2mod[l];
        const float fr  = (float)res;

        // jnp.floor(x * res).astype(int32) % res  -- product provably < res for x in [0,1),
        // keep the conditional subtract as an exact replica of "% res" anyway.
        int c0 = (int)floorf(x0 * fr); if (c0 >= res) c0 -= res;
        int c1 = (int)floorf(x1 * fr); if (c1 >= res) c1 -= res;
        int c2 = (int)floorf(x2 * fr); if (c2 >= res) c2 -= res;

        // h = (c0 % H + (c1*res) % H + (c2*((res*res)%H)) % H) % H
        // all terms non-negative, fit in int32 (max 2047*524287 < 2^31) -> masks are exact
        int h = (c0 + ((c1 * res) & HMASK) + ((c2 * r2) & HMASK)) & HMASK;

        v[l] = e2[l * HSIZE + h];          // 8B gather, independent across levels
    }

    // Pack 16 float2 -> 8 float4, one 128B contiguous region per point.
    float4* __restrict__ o4 = (float4*)(out + (size_t)p * (NLEVELS * 2));
    #pragma unroll
    for (int i = 0; i < 8; ++i) {
        o4[i] = make_float4(v[2 * i].x, v[2 * i].y, v[2 * i + 1].x, v[2 * i + 1].y);
    }
}

extern "C" void kernel_launch(void* const* d_in, const int* in_sizes, int n_in,
                              void* d_out, int out_size, void* d_ws, size_t ws_size,
                              hipStream_t stream)
{
    const float* x   = (const float*)d_in[0];
    const float* emb = (const float*)d_in[1];
    float*       out = (float*)d_out;

    const int npts = in_sizes[0] / 3;

    // Replicate the reference's *host double* resolution computation exactly.
    // CPython's math.exp/log and float.** call the platform libm (glibc), same
    // as std::exp/log/pow here -> identical rounding, including the level-15
    // 16*s^15 == 2048-or-2047 coin flip.
    LevelParams lp;
    const double s = std::exp((std::log(2048.0) - std::log(16.0)) / 15.0);
    for (int l = 0; l < NLEVELS; ++l) {
        const double r = 16.0 * std::pow(s, (double)l);
        const int res  = (int)r;                       // int() truncation
        lp.res[l]   = res;
        lp.r2mod[l] = (int)(((long long)res * res) % HSIZE);
    }

    const int blocks = (npts + 255) / 256;
    hipLaunchKernelGGL(hashgrid_fwd, dim3(blocks), dim3(256), 0, stream,
                       x, emb, out, lp, npts);
}

// Round 2
// 371.322 us; speedup vs baseline: 1.2526x; 1.2526x over previous
//
#include <hip/hip_runtime.h>
#include <cmath>

#define NLEVELS 16
#define HSIZE   (1 << 19)     // hashmap size, power of two
#define HMASK   (HSIZE - 1)

typedef float v2f __attribute__((ext_vector_type(2)));
typedef float v4f __attribute__((ext_vector_type(4)));

struct LevelParams {
    int res[NLEVELS];
    int r2mod[NLEVELS];       // (res*res) % HSIZE
};

__device__ __forceinline__ int hash_one(float x0, float x1, float x2, int res, int r2)
{
    const float fr = (float)res;
    int c0 = (int)floorf(x0 * fr); if (c0 >= res) c0 -= res;
    int c1 = (int)floorf(x1 * fr); if (c1 >= res) c1 -= res;
    int c2 = (int)floorf(x2 * fr); if (c2 >= res) c2 -= res;
    return (c0 + ((c1 * res) & HMASK) + ((c2 * r2) & HMASK)) & HMASK;
}

// ---------------- K1: XCD-affinity gather -------------------------------
// blockIdx % 8 selects a level PAIR {g, 15-g}; with round-robin block->XCD
// dispatch, each XCD's L2 only serves its own ~4-5.5 MB of tables.
// Streaming traffic (x, ws) is non-temporal so it doesn't evict the tables.
__global__ __launch_bounds__(256)
void hashgrid_gather(const float* __restrict__ x,
                     const float* __restrict__ emb,
                     v2f* __restrict__ ws,
                     LevelParams lp, int npts)
{
    __shared__ float sx[256 * 3];

    const int tid   = threadIdx.x;
    const int g     = blockIdx.x & 7;
    const int chunk = blockIdx.x >> 3;
    const int block_base = chunk * 256;

    const int nfl   = npts * 3;
    const int base3 = block_base * 3;
    #pragma unroll
    for (int k = 0; k < 3; ++k) {
        int idx = base3 + tid + k * 256;
        if (idx < nfl) sx[tid + k * 256] = __builtin_nontemporal_load(&x[idx]);
    }
    __syncthreads();

    const int p = block_base + tid;
    if (p >= npts) return;

    const float x0 = sx[tid * 3 + 0];
    const float x1 = sx[tid * 3 + 1];
    const float x2 = sx[tid * 3 + 2];

    const v2f* __restrict__ e2 = (const v2f*)emb;

    const int lA = g;          // coarse half
    const int lB = 15 - g;     // fine half  (pairs: {0,15},{1,14},...,{7,8})

    const int hA = hash_one(x0, x1, x2, lp.res[lA], lp.r2mod[lA]);
    const int hB = hash_one(x0, x1, x2, lp.res[lB], lp.r2mod[lB]);

    const v2f vA = e2[(size_t)lA * HSIZE + hA];   // cached: table lines stay in this XCD's L2
    const v2f vB = e2[(size_t)lB * HSIZE + hB];

    __builtin_nontemporal_store(vA, &ws[(size_t)lA * npts + p]);
    __builtin_nontemporal_store(vB, &ws[(size_t)lB * npts + p]);
}

// ---------------- K2: level-major -> point-major transpose ---------------
// 8 lanes per point; lane j packs levels {2j, 2j+1} into one float4 and the
// wave writes 1 KB contiguous (full 64B lines -> no partial-write inflation).
__global__ __launch_bounds__(256)
void hashgrid_transpose(const v2f* __restrict__ ws,
                        v4f* __restrict__ out4, int npts)
{
    const int t = blockIdx.x * 256 + threadIdx.x;
    const int p = t >> 3;
    const int j = t & 7;
    if (p >= npts) return;

    const v2f a = __builtin_nontemporal_load(&ws[(size_t)(2 * j)     * npts + p]);
    const v2f b = __builtin_nontemporal_load(&ws[(size_t)(2 * j + 1) * npts + p]);

    v4f o; o.x = a.x; o.y = a.y; o.z = b.x; o.w = b.y;
    __builtin_nontemporal_store(o, &out4[(size_t)p * 8 + j]);
}

// ---------------- fallback: proven round-1 single kernel -----------------
__global__ __launch_bounds__(256)
void hashgrid_fwd(const float* __restrict__ x,
                  const float* __restrict__ emb,
                  float* __restrict__ out,
                  LevelParams lp, int npts)
{
    __shared__ float sx[256 * 3];
    const int tid        = threadIdx.x;
    const int block_base = blockIdx.x * 256;
    const int nfl        = npts * 3;
    const int base3      = block_base * 3;
    #pragma unroll
    for (int k = 0; k < 3; ++k) {
        int idx = base3 + tid + k * 256;
        if (idx < nfl) sx[tid + k * 256] = x[idx];
    }
    __syncthreads();
    const int p = block_base + tid;
    if (p >= npts) return;
    const float x0 = sx[tid * 3 + 0], x1 = sx[tid * 3 + 1], x2 = sx[tid * 3 + 2];
    const float2* __restrict__ e2 = (const float2*)emb;
    float2 v[NLEVELS];
    #pragma unroll
    for (int l = 0; l < NLEVELS; ++l) {
        const int h = hash_one(x0, x1, x2, lp.res[l], lp.r2mod[l]);
        v[l] = e2[(size_t)l * HSIZE + h];
    }
    float4* __restrict__ o4 = (float4*)(out + (size_t)p * (NLEVELS * 2));
    #pragma unroll
    for (int i = 0; i < 8; ++i)
        o4[i] = make_float4(v[2 * i].x, v[2 * i].y, v[2 * i + 1].x, v[2 * i + 1].y);
}

extern "C" void kernel_launch(void* const* d_in, const int* in_sizes, int n_in,
                              void* d_out, int out_size, void* d_ws, size_t ws_size,
                              hipStream_t stream)
{
    const float* x   = (const float*)d_in[0];
    const float* emb = (const float*)d_in[1];
    float*       out = (float*)d_out;

    const int npts = in_sizes[0] / 3;

    // Host-double resolution computation, exact replica of the reference
    // (same libm as CPython's math.exp/log and float.**).
    LevelParams lp;
    const double s = std::exp((std::log(2048.0) - std::log(16.0)) / 15.0);
    for (int l = 0; l < NLEVELS; ++l) {
        const double r = 16.0 * std::pow(s, (double)l);
        const int res  = (int)r;
        lp.res[l]   = res;
        lp.r2mod[l] = (int)(((long long)res * res) % HSIZE);
    }

    const size_t ws_need = (size_t)NLEVELS * (size_t)npts * sizeof(v2f);
    if (ws_size >= ws_need) {
        const int chunks  = (npts + 255) / 256;
        const int grid1   = chunks * 8;
        hipLaunchKernelGGL(hashgrid_gather, dim3(grid1), dim3(256), 0, stream,
                           x, emb, (v2f*)d_ws, lp, npts);
        const int grid2 = (npts * 8 + 255) / 256;
        hipLaunchKernelGGL(hashgrid_transpose, dim3(grid2), dim3(256), 0, stream,
                           (const v2f*)d_ws, (v4f*)out, npts);
    } else {
        const int blocks = (npts + 255) / 256;
        hipLaunchKernelGGL(hashgrid_fwd, dim3(blocks), dim3(256), 0, stream,
                           x, emb, out, lp, npts);
    }
}